// Round 7
// baseline (457.638 us; speedup 1.0000x reference)
//
#include <hip/hip_runtime.h>

// Biaffine, right-to-left association, MFMA bf16, pre-cast W:
//   Wb16[o,i,j] = bwn0 * W_bil[o,i,j]            (bf16, j<512, prep once)
//   u512[by,o]  = bwn0*(x2b . W_bil[o,512,:]) + bwn1*(x2 . W_lin[512:,o] + b_lin[o])
//   U'[y,o,i]   = (x2b16 @ Wb16[o]^T) + bwn0*W_bil[o,i,512] + bwn1*W_lin[i,o]  (bf16)
//   out[b,x,y,o]= sum_i x1b16[x,i]*U'[y,o,i] + u512[by,o]
// R7: passA = R6 loop (99us, VGPR 64, conflicts 2.36e6) + R2's bijective XCD
//     o-chunking (32 blocks/o on one XCD -> Wb16 slab L2-resident; R2 measured
//     FETCH 81->43MB). passB = 512-thread 256x x 128o tile, grid 1024 yg:
//     Up read exactly ONCE (saves 134MB), same verified swizzle/fragments.
// ws: x1b16 1MB | x2b16 1MB | u512 .5MB | W512T .25MB | Wb16 64MiB | Up 134MB ~= 195MiB

#define LL 256
#define DD 512
#define OO 128
#define BB 4
#define WB_OI 263169   // 513*513
#define WB_R512 262656 // 512*513

typedef __attribute__((ext_vector_type(8))) short  short8;
typedef __attribute__((ext_vector_type(8))) unsigned short us8;
typedef __attribute__((ext_vector_type(4))) unsigned short us4;
typedef __attribute__((ext_vector_type(4))) float  f32x4;

__device__ __forceinline__ unsigned short f2bf(float f) {
    unsigned int u = __builtin_bit_cast(unsigned int, f);
    u = (u + 0x7FFFu + ((u >> 16) & 1u)) >> 16;
    return (unsigned short)u;
}
__device__ __forceinline__ float bf2f(unsigned short s) {
    return __builtin_bit_cast(float, (unsigned int)s << 16);
}
__device__ __forceinline__ void load_lds16(const void* g, void* l) {
    __builtin_amdgcn_global_load_lds(
        (const __attribute__((address_space(1))) unsigned int*)g,
        (__attribute__((address_space(3))) unsigned int*)l, 16, 0, 0);
}

// ---- fused: cast fp32->bf16 (x1,x2) + W512T transpose, one launch ----
__global__ __launch_bounds__(256) void castprep_kernel(
    const float* __restrict__ x1, const float* __restrict__ x2,
    unsigned short* __restrict__ x1b, unsigned short* __restrict__ x2b,
    const float* __restrict__ Wb, float* __restrict__ W512T)
{
    const int bid = blockIdx.x;
    if (bid < 1024) {
        int i = bid * 256 + threadIdx.x;            // 0 .. 262143
        const float* s; unsigned short* d; int j;
        if (i < 131072) { s = x1; d = x1b; j = i; }
        else            { s = x2; d = x2b; j = i - 131072; }
        float4 v = ((const float4*)s)[j];
        us4 u; u.x = f2bf(v.x); u.y = f2bf(v.y); u.z = f2bf(v.z); u.w = f2bf(v.w);
        *(us4*)(d + (size_t)j * 4) = u;
    } else {
        int idx = (bid - 1024) * 256 + threadIdx.x; // j*128 + o
        if (idx < 513 * 128) {
            const int o = idx & 127, j = idx >> 7;
            W512T[idx] = Wb[(size_t)o * WB_OI + WB_R512 + j];
        }
    }
}

// ---- prep: Wb16[o*512+i][j] = bf16(bwn0 * W_bil[o,i,j]), j<512. 4 rows/block. ----
__global__ __launch_bounds__(256) void prepw_kernel(
    const float* __restrict__ Wb, const float* __restrict__ bw,
    unsigned short* __restrict__ Wb16)
{
    const int t = threadIdx.x;
    const int row = blockIdx.x * 4 + (t >> 6);   // o*512 + i
    const int o = row >> 9, i = row & 511;
    const int l = t & 63;
    const float e0 = __expf(bw[0]), e1 = __expf(bw[1]);
    const float bwn0 = e0 / (e0 + e1);
    const float* src = Wb + (size_t)o * WB_OI + (size_t)i * 513;
    unsigned short* dst = Wb16 + (size_t)row * 512;
    float v[8];
    #pragma unroll
    for (int e = 0; e < 8; ++e) v[e] = src[e * 64 + l];
    #pragma unroll
    for (int e = 0; e < 8; ++e) dst[e * 64 + l] = f2bf(bwn0 * v[e]);
}

// ---- u512[by,o], all batches, linear path folded; coalesced via W512T ----
__global__ __launch_bounds__(128) void u512_kernel(
    const float* __restrict__ x2, const float* __restrict__ W512T,
    const float* __restrict__ W_lin, const float* __restrict__ b_lin,
    const float* __restrict__ bw, float* __restrict__ u512buf)
{
    __shared__ float xs[DD];
    const int by = blockIdx.x;   // 0..1023
    const int o  = threadIdx.x;
    const float* xr = x2 + (size_t)by * DD;
    for (int j = o; j < DD; j += 128) xs[j] = xr[j];
    __syncthreads();
    float s1 = W512T[512 * 128 + o];    // j=512 (ones col of x2b)
    float s2 = b_lin[o];
    #pragma unroll 4
    for (int j = 0; j < DD; ++j) {
        s1 += xs[j] * W512T[j * 128 + o];
        s2 += xs[j] * W_lin[(size_t)(DD + j) * OO + o];
    }
    const float e0 = __expf(bw[0]), e1 = __expf(bw[1]);
    const float bwn0 = e0 / (e0 + e1), bwn1 = e1 / (e0 + e1);
    u512buf[(size_t)by * OO + o] = bwn0 * s1 + bwn1 * s2;
}

// ---- pass A: U'[yg,o,i] = (x2b16 @ Wb16[o]^T) + corr[i]; 128x128 tile, K=512 ----
// 1-D grid 4096, bijective XCD chunk: XCD c owns lin [c*512,(c+1)*512) ->
// o in [c*16,(c+1)*16): each o's 32 (ib,yg) blocks co-located -> Wb16 slab
// (512KB) L2-resident (R2 measured FETCH 81->43MB). Loop/epilogue = R6 verbatim.
__global__ __launch_bounds__(256, 4) void passA_kernel(
    const unsigned short* __restrict__ x2b, const unsigned short* __restrict__ Wb16,
    const float* __restrict__ W_bil, const float* __restrict__ W_lin,
    const float* __restrict__ bw, unsigned short* __restrict__ Up)
{
    __shared__ __align__(16) char smem[33280];
    unsigned short* As0 = (unsigned short*)smem;             // [128 y][32 j] 8KB
    unsigned short* Bs0 = (unsigned short*)(smem + 8192);    // [128 i][32 j] 8KB
    unsigned short* As1 = (unsigned short*)(smem + 16384);
    unsigned short* Bs1 = (unsigned short*)(smem + 24576);
    unsigned short* Cs  = (unsigned short*)smem;             // [64][136] epilogue reuse
    float* corr = (float*)(smem + 32768);                    // [128]

    const int t = threadIdx.x, w = t >> 6, l = t & 63;
    const int id  = blockIdx.x;                  // 0..4095
    const int lin = (id & 7) * 512 + (id >> 3);  // bijective XCD chunking
    const int o   = lin >> 5;                    // 16 consecutive o per XCD chunk
    const int ib  = (lin & 3) * 128;
    const int yg  = ((lin >> 2) & 7) * 128;
    const int wy = w & 1, wx = w >> 1;

    f32x4 acc[4][4] = {};
    const unsigned short* Wo16 = Wb16 + (size_t)o * DD * DD;

    const int rb0 = w * 32;
    const int rr  = l >> 2;                              // 0..15
    const int kof = ((l & 3) ^ ((l >> 3) & 3)) * 8;      // pre-swizzled source chunk

#define STAGE_A(ASP, BSP, K0) do {                                              \
    _Pragma("unroll")                                                           \
    for (int q = 0; q < 2; ++q) {                                               \
        const int rb = rb0 + q * 16, rrow = rb + rr, ko = (K0) + kof;           \
        load_lds16(x2b  + (size_t)(yg + rrow) * DD + ko, (ASP) + rb * 32);      \
        load_lds16(Wo16 + (size_t)(ib + rrow) * DD + ko, (BSP) + rb * 32);      \
    } } while (0)

    STAGE_A(As0, Bs0, 0);
    __syncthreads();

    const int mrow = wy * 64 + (l & 15);
    const int ncol = wx * 64 + (l & 15);
    const int psel = ((l >> 4) ^ ((l >> 1) & 3)) * 8;    // swizzled read slot

    #pragma unroll 2
    for (int kt = 0; kt < 16; ++kt) {
        const int cur = kt & 1;
        unsigned short* Asr = cur ? As1 : As0;
        unsigned short* Bsr = cur ? Bs1 : Bs0;
        unsigned short* Asn = cur ? As0 : As1;
        unsigned short* Bsn = cur ? Bs0 : Bs1;
        if (kt < 15) STAGE_A(Asn, Bsn, (kt + 1) * 32);
        short8 af[4], bfr[4];
        #pragma unroll
        for (int mt = 0; mt < 4; ++mt) af[mt]  = *(const short8*)(Asr + (mrow + mt * 16) * 32 + psel);
        #pragma unroll
        for (int nt = 0; nt < 4; ++nt) bfr[nt] = *(const short8*)(Bsr + (ncol + nt * 16) * 32 + psel);
        #pragma unroll
        for (int mt = 0; mt < 4; ++mt)
            #pragma unroll
            for (int nt = 0; nt < 4; ++nt)
                acc[mt][nt] = __builtin_amdgcn_mfma_f32_16x16x32_bf16(af[mt], bfr[nt], acc[mt][nt], 0, 0, 0);
        __syncthreads();   // drains own stage (vmcnt) + all waves' reads of cur
    }
#undef STAGE_A

    const float e0 = __expf(bw[0]), e1 = __expf(bw[1]);
    const float bwn0 = e0 / (e0 + e1), bwn1 = e1 / (e0 + e1);
    if (t < 128) {
        const int ig = ib + t;
        corr[t] = bwn1 * W_lin[(size_t)ig * OO + o]
                + bwn0 * W_bil[(size_t)o * WB_OI + (size_t)ig * 513 + 512];
    }
    // two-half epilogue through 64x136 LDS transpose buffer
    #pragma unroll
    for (int half = 0; half < 2; ++half) {
        if (wy == half) {
            #pragma unroll
            for (int mt = 0; mt < 4; ++mt) {
                const int yl = mt * 16 + ((l >> 4) << 2);   // local row in half
                #pragma unroll
                for (int nt = 0; nt < 4; ++nt) {
                    const int ic = wx * 64 + nt * 16 + (l & 15);
                    #pragma unroll
                    for (int r = 0; r < 4; ++r)
                        Cs[(yl + r) * 136 + ic] = f2bf(acc[mt][nt][r]);
                }
            }
        }
        __syncthreads();
        #pragma unroll
        for (int p = 0; p < 4; ++p) {
            const int yl = p * 16 + (t >> 4);
            const int i0 = (t & 15) * 8;
            short8 v = *(const short8*)(Cs + yl * 136 + i0);
            us8 uo;
            #pragma unroll
            for (int e = 0; e < 8; ++e)
                uo[e] = f2bf(bf2f((unsigned short)v[e]) + corr[i0 + e]);
            *(us8*)(Up + ((size_t)(yg + half * 64 + yl) * OO + o) * DD + ib + i0) = uo;
        }
        __syncthreads();
    }
}

// ---- pass B: out[b,x,y,:] = x1b16 @ U'[yg]^T + u512[yg,:] ----
// grid 1024 yg, block 512 (8 waves: (w>>1) x-quarter, (w&1) o-half).
// Per-block tile 256x by 128o -> Up slab [yg] read exactly once.
__global__ __launch_bounds__(512, 4) void passB_kernel(
    const unsigned short* __restrict__ x1b, const unsigned short* __restrict__ Up,
    const float* __restrict__ u512buf, float* __restrict__ out)
{
    __shared__ __align__(16) char smem[49664];   // 2 x (A 16KB + B 8KB) + u5 512B
    float* u5 = (float*)(smem + 49152);          // [128]

    const int t = threadIdx.x, w = t >> 6, l = t & 63;
    const int yg = blockIdx.x;           // 0..1023
    const int bb = yg >> 8, y = yg & 255;
    const int wxm = w >> 1, wxo = w & 1;
    if (t < 128) u5[t] = u512buf[(size_t)yg * OO + t];

    f32x4 acc[4][4] = {};
    const unsigned short* Abase = x1b + (size_t)bb * LL * DD;   // 256 x-rows
    const unsigned short* Bbase = Up + (size_t)yg * OO * DD;    // 128 o-rows

    const int arow = t >> 2;                             // 0..127
    const int kof  = ((t & 3) ^ ((t >> 3) & 3)) * 8;     // pre-swizzled source chunk
    // dest: row r, phys chunk t&3 -> As_[r*32 + (t&3)*8] = As_[q*4096 + t*8] (linear)

#define STAGE_B(S, K0) do {                                                     \
    unsigned short* As_ = (unsigned short*)(smem + (S) * 24576);                \
    unsigned short* Bs_ = As_ + 8192;                                           \
    const int ko = (K0) + kof;                                                  \
    load_lds16(Abase + (size_t)arow * DD + ko,         As_ + t * 8);            \
    load_lds16(Abase + (size_t)(128 + arow) * DD + ko, As_ + 4096 + t * 8);     \
    load_lds16(Bbase + (size_t)arow * DD + ko,         Bs_ + t * 8);            \
  } while (0)

    STAGE_B(0, 0);
    __syncthreads();

    const int mrow = wxm * 64 + (l & 15);                // x-row frag base (256 rows)
    const int ncol = wxo * 64 + (l & 15);                // o-row frag base (128 rows)
    const int psel = ((l >> 4) ^ ((l >> 1) & 3)) * 8;

    #pragma unroll 2
    for (int kt = 0; kt < 16; ++kt) {
        const int cur = kt & 1;
        if (kt < 15) STAGE_B(cur ^ 1, (kt + 1) * 32);
        const unsigned short* As_ = (const unsigned short*)(smem + cur * 24576);
        const unsigned short* Bs_ = As_ + 8192;
        short8 af[4], bfr[4];
        #pragma unroll
        for (int mt = 0; mt < 4; ++mt) af[mt]  = *(const short8*)(As_ + (mrow + mt * 16) * 32 + psel);
        #pragma unroll
        for (int nt = 0; nt < 4; ++nt) bfr[nt] = *(const short8*)(Bs_ + (ncol + nt * 16) * 32 + psel);
        #pragma unroll
        for (int mt = 0; mt < 4; ++mt)
            #pragma unroll
            for (int nt = 0; nt < 4; ++nt)
                acc[mt][nt] = __builtin_amdgcn_mfma_f32_16x16x32_bf16(af[mt], bfr[nt], acc[mt][nt], 0, 0, 0);
        __syncthreads();
    }
#undef STAGE_B

    #pragma unroll
    for (int mt = 0; mt < 4; ++mt) {
        const int xr = wxm * 64 + mt * 16 + ((l >> 4) << 2);
        #pragma unroll
        for (int nt = 0; nt < 4; ++nt) {
            const int oc = wxo * 64 + nt * 16 + (l & 15);
            const float c = u5[oc];
            #pragma unroll
            for (int r = 0; r < 4; ++r)
                out[((size_t)(bb * LL + xr + r) * LL + y) * OO + oc] = acc[mt][nt][r] + c;
        }
    }
}

extern "C" void kernel_launch(void* const* d_in, const int* in_sizes, int n_in,
                              void* d_out, int out_size, void* d_ws, size_t ws_size,
                              hipStream_t stream)
{
    const float* x1    = (const float*)d_in[0];
    const float* x2    = (const float*)d_in[1];
    const float* bw    = (const float*)d_in[2];
    const float* W_bil = (const float*)d_in[3];
    const float* W_lin = (const float*)d_in[4];
    const float* b_lin = (const float*)d_in[5];
    float* out = (float*)d_out;

    char* ws = (char*)d_ws;
    unsigned short* x1b16 = (unsigned short*)ws;                         // 1 MB
    unsigned short* x2b16 = (unsigned short*)(ws + (1u << 20));          // 1 MB
    float*          u512b = (float*)(ws + (2u << 20));                   // 512 KB
    float*          W512T = (float*)(ws + (2u << 20) + (512u << 10));    // 257 KB
    unsigned short* Wb16  = (unsigned short*)(ws + (3u << 20));          // 64 MiB
    unsigned short* Up    = (unsigned short*)(ws + (3u << 20) + ((size_t)128 * 512 * 512 * 2)); // 134 MB

    castprep_kernel<<<1281, 256, 0, stream>>>(x1, x2, x1b16, x2b16, W_bil, W512T);
    prepw_kernel<<<16384, 256, 0, stream>>>(W_bil, bw, Wb16);
    u512_kernel<<<BB * LL, 128, 0, stream>>>(x2, W512T, W_lin, b_lin, bw, u512b);

    passA_kernel<<<4096, 256, 0, stream>>>(x2b16, Wb16, W_bil, W_lin, bw, Up);
    passB_kernel<<<1024, 512, 0, stream>>>(x1b16, Up, u512b, out);
}

// Round 8
// 444.793 us; speedup vs baseline: 1.0289x; 1.0289x over previous
//
#include <hip/hip_runtime.h>

// Biaffine, right-to-left association, MFMA bf16, pre-cast W:
//   Wb16[o,i,j] = bwn0 * W_bil[o,i,j]            (bf16, j<512, prep once)
//   u512[by,o]  = bwn0*(x2b . W_bil[o,512,:]) + bwn1*(x2 . W_lin[512:,o] + b_lin[o])
//   U'[y,o,i]   = (x2b16 @ Wb16[o]^T) + bwn0*W_bil[o,i,512] + bwn1*W_lin[i,o]  (bf16)
//   out[b,x,y,o]= sum_i x1b16[x,i]*U'[y,o,i] + u512[by,o]
// R8: consolidation of measured bests. passA = R6 verbatim (99us: default
//     (4,8,128) grid — R7 proved XCD chunking hurts despite lower FETCH;
//     VGPR 64 via launch_bounds(256,4); correct swizzle, conflicts 2.36e6).
//     passB = R7 verbatim (512 thr, 256x*128o tile, Up read exactly once;
//     write-bound at 537MB out). prepw+casts+W512T merged into one launch.
// ws: x1b16 1MB | x2b16 1MB | u512 .5MB | W512T .25MB | Wb16 64MiB | Up 134MB ~= 195MiB

#define LL 256
#define DD 512
#define OO 128
#define BB 4
#define WB_OI 263169   // 513*513
#define WB_R512 262656 // 512*513

typedef __attribute__((ext_vector_type(8))) short  short8;
typedef __attribute__((ext_vector_type(8))) unsigned short us8;
typedef __attribute__((ext_vector_type(4))) unsigned short us4;
typedef __attribute__((ext_vector_type(4))) float  f32x4;

__device__ __forceinline__ unsigned short f2bf(float f) {
    unsigned int u = __builtin_bit_cast(unsigned int, f);
    u = (u + 0x7FFFu + ((u >> 16) & 1u)) >> 16;
    return (unsigned short)u;
}
__device__ __forceinline__ float bf2f(unsigned short s) {
    return __builtin_bit_cast(float, (unsigned int)s << 16);
}
__device__ __forceinline__ void load_lds16(const void* g, void* l) {
    __builtin_amdgcn_global_load_lds(
        (const __attribute__((address_space(1))) unsigned int*)g,
        (__attribute__((address_space(3))) unsigned int*)l, 16, 0, 0);
}

// ---- merged prep: [0,16384) Wb16 cast+scale | [16384,17408) x1/x2 bf16 cast
//      | [17408,17665) W512T transpose. One launch, three independent jobs. ----
__global__ __launch_bounds__(256) void prep_kernel(
    const float* __restrict__ x1, const float* __restrict__ x2,
    unsigned short* __restrict__ x1b, unsigned short* __restrict__ x2b,
    const float* __restrict__ Wb, const float* __restrict__ bw,
    unsigned short* __restrict__ Wb16, float* __restrict__ W512T)
{
    const int bid = blockIdx.x;
    const int t = threadIdx.x;
    if (bid < 16384) {
        // Wb16[o*512+i][j] = bf16(bwn0 * W_bil[o,i,j]), 4 rows/block,
        // lane-interleaved scalar dword loads (row stride 513 -> float4 unaligned).
        const int row = bid * 4 + (t >> 6);   // o*512 + i
        const int o = row >> 9, i = row & 511;
        const int l = t & 63;
        const float e0 = __expf(bw[0]), e1 = __expf(bw[1]);
        const float bwn0 = e0 / (e0 + e1);
        const float* src = Wb + (size_t)o * WB_OI + (size_t)i * 513;
        unsigned short* dst = Wb16 + (size_t)row * 512;
        float v[8];
        #pragma unroll
        for (int e = 0; e < 8; ++e) v[e] = src[e * 64 + l];
        #pragma unroll
        for (int e = 0; e < 8; ++e) dst[e * 64 + l] = f2bf(bwn0 * v[e]);
    } else if (bid < 17408) {
        int i = (bid - 16384) * 256 + t;      // 0 .. 262143 (2 * 131072 float4)
        const float* s; unsigned short* d; int j;
        if (i < 131072) { s = x1; d = x1b; j = i; }
        else            { s = x2; d = x2b; j = i - 131072; }
        float4 v = ((const float4*)s)[j];
        us4 u; u.x = f2bf(v.x); u.y = f2bf(v.y); u.z = f2bf(v.z); u.w = f2bf(v.w);
        *(us4*)(d + (size_t)j * 4) = u;
    } else {
        int idx = (bid - 17408) * 256 + t;    // j*128 + o
        if (idx < 513 * 128) {
            const int o = idx & 127, j = idx >> 7;
            W512T[idx] = Wb[(size_t)o * WB_OI + WB_R512 + j];
        }
    }
}

// ---- u512[by,o], all batches, linear path folded; coalesced via W512T ----
__global__ __launch_bounds__(128) void u512_kernel(
    const float* __restrict__ x2, const float* __restrict__ W512T,
    const float* __restrict__ W_lin, const float* __restrict__ b_lin,
    const float* __restrict__ bw, float* __restrict__ u512buf)
{
    __shared__ float xs[DD];
    const int by = blockIdx.x;   // 0..1023
    const int o  = threadIdx.x;
    const float* xr = x2 + (size_t)by * DD;
    for (int j = o; j < DD; j += 128) xs[j] = xr[j];
    __syncthreads();
    float s1 = W512T[512 * 128 + o];    // j=512 (ones col of x2b)
    float s2 = b_lin[o];
    #pragma unroll 4
    for (int j = 0; j < DD; ++j) {
        s1 += xs[j] * W512T[j * 128 + o];
        s2 += xs[j] * W_lin[(size_t)(DD + j) * OO + o];
    }
    const float e0 = __expf(bw[0]), e1 = __expf(bw[1]);
    const float bwn0 = e0 / (e0 + e1), bwn1 = e1 / (e0 + e1);
    u512buf[(size_t)by * OO + o] = bwn0 * s1 + bwn1 * s2;
}

// ---- pass A: U'[yg,o,i] = (x2b16 @ Wb16[o]^T) + corr[i]; 128x128 tile, K=512 ----
// grid (4 i-tiles, 8 y-tiles, 128 o), block 256 (2x2 waves). R6 verbatim:
// 2-stage dbuf BK=32, STAGE(next) before compute(cur), one __syncthreads/tile.
// Swizzle: phys chunk p of row r holds logical p ^ ((r>>1)&3); source side
// kof = ((l&3)^((l>>3)&3))*8, read side psel = ((l>>4)^((l>>1)&3))*8.
__global__ __launch_bounds__(256, 4) void passA_kernel(
    const unsigned short* __restrict__ x2b, const unsigned short* __restrict__ Wb16,
    const float* __restrict__ W_bil, const float* __restrict__ W_lin,
    const float* __restrict__ bw, unsigned short* __restrict__ Up)
{
    __shared__ __align__(16) char smem[33280];
    unsigned short* As0 = (unsigned short*)smem;             // [128 y][32 j] 8KB
    unsigned short* Bs0 = (unsigned short*)(smem + 8192);    // [128 i][32 j] 8KB
    unsigned short* As1 = (unsigned short*)(smem + 16384);
    unsigned short* Bs1 = (unsigned short*)(smem + 24576);
    unsigned short* Cs  = (unsigned short*)smem;             // [64][136] epilogue reuse
    float* corr = (float*)(smem + 32768);                    // [128]

    const int t = threadIdx.x, w = t >> 6, l = t & 63;
    const int ib = blockIdx.x * 128;
    const int yg = blockIdx.y * 128;     // global row 0..1023 (batch folded in)
    const int o  = blockIdx.z;
    const int wy = w & 1, wx = w >> 1;

    f32x4 acc[4][4] = {};
    const unsigned short* Wo16 = Wb16 + (size_t)o * DD * DD;

    const int rb0 = w * 32;
    const int rr  = l >> 2;                              // 0..15
    const int kof = ((l & 3) ^ ((l >> 3) & 3)) * 8;      // pre-swizzled source chunk

#define STAGE_A(ASP, BSP, K0) do {                                              \
    _Pragma("unroll")                                                           \
    for (int q = 0; q < 2; ++q) {                                               \
        const int rb = rb0 + q * 16, rrow = rb + rr, ko = (K0) + kof;           \
        load_lds16(x2b  + (size_t)(yg + rrow) * DD + ko, (ASP) + rb * 32);      \
        load_lds16(Wo16 + (size_t)(ib + rrow) * DD + ko, (BSP) + rb * 32);      \
    } } while (0)

    STAGE_A(As0, Bs0, 0);
    __syncthreads();

    const int mrow = wy * 64 + (l & 15);
    const int ncol = wx * 64 + (l & 15);
    const int psel = ((l >> 4) ^ ((l >> 1) & 3)) * 8;    // swizzled read slot

    #pragma unroll 2
    for (int kt = 0; kt < 16; ++kt) {
        const int cur = kt & 1;
        unsigned short* Asr = cur ? As1 : As0;
        unsigned short* Bsr = cur ? Bs1 : Bs0;
        unsigned short* Asn = cur ? As0 : As1;
        unsigned short* Bsn = cur ? Bs0 : Bs1;
        if (kt < 15) STAGE_A(Asn, Bsn, (kt + 1) * 32);
        short8 af[4], bfr[4];
        #pragma unroll
        for (int mt = 0; mt < 4; ++mt) af[mt]  = *(const short8*)(Asr + (mrow + mt * 16) * 32 + psel);
        #pragma unroll
        for (int nt = 0; nt < 4; ++nt) bfr[nt] = *(const short8*)(Bsr + (ncol + nt * 16) * 32 + psel);
        #pragma unroll
        for (int mt = 0; mt < 4; ++mt)
            #pragma unroll
            for (int nt = 0; nt < 4; ++nt)
                acc[mt][nt] = __builtin_amdgcn_mfma_f32_16x16x32_bf16(af[mt], bfr[nt], acc[mt][nt], 0, 0, 0);
        __syncthreads();   // drains own stage (vmcnt) + all waves' reads of cur
    }
#undef STAGE_A

    const float e0 = __expf(bw[0]), e1 = __expf(bw[1]);
    const float bwn0 = e0 / (e0 + e1), bwn1 = e1 / (e0 + e1);
    if (t < 128) {
        const int ig = ib + t;
        corr[t] = bwn1 * W_lin[(size_t)ig * OO + o]
                + bwn0 * W_bil[(size_t)o * WB_OI + (size_t)ig * 513 + 512];
    }
    // two-half epilogue through 64x136 LDS transpose buffer
    #pragma unroll
    for (int half = 0; half < 2; ++half) {
        if (wy == half) {
            #pragma unroll
            for (int mt = 0; mt < 4; ++mt) {
                const int yl = mt * 16 + ((l >> 4) << 2);   // local row in half
                #pragma unroll
                for (int nt = 0; nt < 4; ++nt) {
                    const int ic = wx * 64 + nt * 16 + (l & 15);
                    #pragma unroll
                    for (int r = 0; r < 4; ++r)
                        Cs[(yl + r) * 136 + ic] = f2bf(acc[mt][nt][r]);
                }
            }
        }
        __syncthreads();
        #pragma unroll
        for (int p = 0; p < 4; ++p) {
            const int yl = p * 16 + (t >> 4);
            const int i0 = (t & 15) * 8;
            short8 v = *(const short8*)(Cs + yl * 136 + i0);
            us8 uo;
            #pragma unroll
            for (int e = 0; e < 8; ++e)
                uo[e] = f2bf(bf2f((unsigned short)v[e]) + corr[i0 + e]);
            *(us8*)(Up + ((size_t)(yg + half * 64 + yl) * OO + o) * DD + ib + i0) = uo;
        }
        __syncthreads();
    }
}

// ---- pass B: out[b,x,y,:] = x1b16 @ U'[yg]^T + u512[yg,:] ----
// grid 1024 yg, block 512 (8 waves: (w>>1) x-quarter, (w&1) o-half).
// Per-block tile 256x by 128o -> Up slab [yg] read exactly once. R7 verbatim.
__global__ __launch_bounds__(512, 4) void passB_kernel(
    const unsigned short* __restrict__ x1b, const unsigned short* __restrict__ Up,
    const float* __restrict__ u512buf, float* __restrict__ out)
{
    __shared__ __align__(16) char smem[49664];   // 2 x (A 16KB + B 8KB) + u5 512B
    float* u5 = (float*)(smem + 49152);          // [128]

    const int t = threadIdx.x, w = t >> 6, l = t & 63;
    const int yg = blockIdx.x;           // 0..1023
    const int bb = yg >> 8, y = yg & 255;
    const int wxm = w >> 1, wxo = w & 1;
    if (t < 128) u5[t] = u512buf[(size_t)yg * OO + t];

    f32x4 acc[4][4] = {};
    const unsigned short* Abase = x1b + (size_t)bb * LL * DD;   // 256 x-rows
    const unsigned short* Bbase = Up + (size_t)yg * OO * DD;    // 128 o-rows

    const int arow = t >> 2;                             // 0..127
    const int kof  = ((t & 3) ^ ((t >> 3) & 3)) * 8;     // pre-swizzled source chunk

#define STAGE_B(S, K0) do {                                                     \
    unsigned short* As_ = (unsigned short*)(smem + (S) * 24576);                \
    unsigned short* Bs_ = As_ + 8192;                                           \
    const int ko = (K0) + kof;                                                  \
    load_lds16(Abase + (size_t)arow * DD + ko,         As_ + t * 8);            \
    load_lds16(Abase + (size_t)(128 + arow) * DD + ko, As_ + 4096 + t * 8);     \
    load_lds16(Bbase + (size_t)arow * DD + ko,         Bs_ + t * 8);            \
  } while (0)

    STAGE_B(0, 0);
    __syncthreads();

    const int mrow = wxm * 64 + (l & 15);                // x-row frag base (256 rows)
    const int ncol = wxo * 64 + (l & 15);                // o-row frag base (128 rows)
    const int psel = ((l >> 4) ^ ((l >> 1) & 3)) * 8;

    #pragma unroll 2
    for (int kt = 0; kt < 16; ++kt) {
        const int cur = kt & 1;
        if (kt < 15) STAGE_B(cur ^ 1, (kt + 1) * 32);
        const unsigned short* As_ = (const unsigned short*)(smem + cur * 24576);
        const unsigned short* Bs_ = As_ + 8192;
        short8 af[4], bfr[4];
        #pragma unroll
        for (int mt = 0; mt < 4; ++mt) af[mt]  = *(const short8*)(As_ + (mrow + mt * 16) * 32 + psel);
        #pragma unroll
        for (int nt = 0; nt < 4; ++nt) bfr[nt] = *(const short8*)(Bs_ + (ncol + nt * 16) * 32 + psel);
        #pragma unroll
        for (int mt = 0; mt < 4; ++mt)
            #pragma unroll
            for (int nt = 0; nt < 4; ++nt)
                acc[mt][nt] = __builtin_amdgcn_mfma_f32_16x16x32_bf16(af[mt], bfr[nt], acc[mt][nt], 0, 0, 0);
        __syncthreads();
    }
#undef STAGE_B

    #pragma unroll
    for (int mt = 0; mt < 4; ++mt) {
        const int xr = wxm * 64 + mt * 16 + ((l >> 4) << 2);
        #pragma unroll
        for (int nt = 0; nt < 4; ++nt) {
            const int oc = wxo * 64 + nt * 16 + (l & 15);
            const float c = u5[oc];
            #pragma unroll
            for (int r = 0; r < 4; ++r)
                out[((size_t)(bb * LL + xr + r) * LL + y) * OO + oc] = acc[mt][nt][r] + c;
        }
    }
}

extern "C" void kernel_launch(void* const* d_in, const int* in_sizes, int n_in,
                              void* d_out, int out_size, void* d_ws, size_t ws_size,
                              hipStream_t stream)
{
    const float* x1    = (const float*)d_in[0];
    const float* x2    = (const float*)d_in[1];
    const float* bw    = (const float*)d_in[2];
    const float* W_bil = (const float*)d_in[3];
    const float* W_lin = (const float*)d_in[4];
    const float* b_lin = (const float*)d_in[5];
    float* out = (float*)d_out;

    char* ws = (char*)d_ws;
    unsigned short* x1b16 = (unsigned short*)ws;                         // 1 MB
    unsigned short* x2b16 = (unsigned short*)(ws + (1u << 20));          // 1 MB
    float*          u512b = (float*)(ws + (2u << 20));                   // 512 KB
    float*          W512T = (float*)(ws + (2u << 20) + (512u << 10));    // 257 KB
    unsigned short* Wb16  = (unsigned short*)(ws + (3u << 20));          // 64 MiB
    unsigned short* Up    = (unsigned short*)(ws + (3u << 20) + ((size_t)128 * 512 * 512 * 2)); // 134 MB

    prep_kernel<<<17665, 256, 0, stream>>>(x1, x2, x1b16, x2b16, W_bil, bw, Wb16, W512T);
    u512_kernel<<<BB * LL, 128, 0, stream>>>(x2, W512T, W_lin, b_lin, bw, u512b);

    passA_kernel<<<dim3(4, 8, OO), 256, 0, stream>>>(x2b16, Wb16, W_bil, W_lin, bw, Up);
    passB_kernel<<<1024, 512, 0, stream>>>(x1b16, Up, u512b, out);
}